// Round 2
// 155.491 us; speedup vs baseline: 1.1401x; 1.1401x over previous
//
#include <hip/hip_runtime.h>

// EnhancedMoEModel: B=524288, D=32, H=64, H2=32, E=8, O=1. fp32 in/out.
// out[b] = sum_e sigmoid(relu(relu(x W1e + b1e) W2e + b2e) W3e + b3e) * probs[b,e]
//
// R12b: same as R12 (expert-loop unroll 2, bf16->f16 with relu-after-pack,
// conflict-free prologue F=tid+1024k, b3 folded into L3 MFMA C), with the
// cvt_pkrtz union element type fixed to __fp16 (the builtin's return type).
//
// Fragment math (verified R8/R10 end-to-end, dtype-independent C/D layout):
// 16x16x32 MFMA with A[m=lane&15][k=8q+j], B[k=8q+j][n=lane&15],
// D[m=4q+r][n]: per-lane reg r. Hidden-unit column permutation
// hmap(mt,n)=32(mt>>1)+8(n>>2)+4(mt&1)+(n&3) makes layer-N output registers
// exactly the next layer's B-fragment.

typedef __attribute__((ext_vector_type(8))) _Float16 f16x8;
typedef __attribute__((ext_vector_type(2))) __fp16 h16x2;
typedef __attribute__((ext_vector_type(4))) float f32x4;

__device__ __forceinline__ unsigned pkh(float lo, float hi) {
    union { h16x2 v; unsigned u; } t;
    t.v = __builtin_amdgcn_cvt_pkrtz(lo, hi);
    return t.u;
}

// packed relu on 2 x f16 (relu-after-pack == relu-before-pack for RTZ:
// negative inputs round to negative f16, max with 0 still yields 0; +0/-0
// both compare equal and max returns the non-negative-zero operand order —
// output of relu on any negative is exactly +0 or -0, and downstream MFMA
// treats -0 * w + c == c, so identical).
__device__ __forceinline__ unsigned relu2(unsigned a) {
    unsigned r;
    asm("v_pk_max_f16 %0, %1, 0" : "=v"(r) : "v"(a));
    return r;
}

#define MFMA32(a, b, c) __builtin_amdgcn_mfma_f32_16x16x32_f16((a), (b), (c), 0, 0, 0)

__global__ __launch_bounds__(1024, 8)
void moe_fused(const float* __restrict__ x, const float* __restrict__ probs,
               const float* __restrict__ W1, const float* __restrict__ b1,
               const float* __restrict__ W2, const float* __restrict__ b2,
               const float* __restrict__ W3, const float* __restrict__ b3,
               float* __restrict__ out) {
    // LDS image, 16-B fragments, byte addr = F*16:
    //   w1: F = e*256 + 64*mt + 16*q + n      (F in [0,2048))
    //   w2: F = 2048 + e*256 + 128*kb2 + 64*mt2 + 16*q + n
    __shared__ short wlds[32768];   // 64 KB exactly
    const int tid = threadIdx.x;
    const int w = tid >> 6, lane = tid & 63, n = lane & 15, q = lane >> 4;

    // ---- prologue: each thread builds 4 fragments (64 B) of the LDS image.
    // F = tid + 1024k: adjacent lanes write adjacent 16-B fragments ->
    // ds_write_b128 conflict-free. Decode depends only on F, so any
    // (tid,k)->F bijection is valid.
    #pragma unroll
    for (int k = 0; k < 4; ++k) {
        const int F = tid + k * 1024;
        const int e = (F >> 8) & 7, s = F & 255;
        const int qq = (s >> 4) & 3, nn = s & 15;
        const float* src;
        int stride;
        if (F < 2048) {          // W1[e][d=8qq+j][hmap(mt,nn)], j strides d
            const int mt = s >> 6;
            const int h = 32 * (mt >> 1) + 8 * (nn >> 2) + 4 * (mt & 1) + (nn & 3);
            src = W1 + (e * 32 + 8 * qq) * 64 + h;
            stride = 64;
        } else {                 // W2[e][h=32kb2+8qq+j][h2map(mt2,nn)], j strides h
            const int kb2 = (s >> 7) & 1, mt2 = (s >> 6) & 1;
            const int h2 = 8 * (nn >> 2) + 4 * mt2 + (nn & 3);
            src = W2 + (e * 64 + 32 * kb2 + 8 * qq) * 32 + h2;
            stride = 32;
        }
        union { f16x8 v; unsigned u[4]; } t;
        t.u[0] = pkh(src[0 * stride], src[1 * stride]);
        t.u[1] = pkh(src[2 * stride], src[3 * stride]);
        t.u[2] = pkh(src[4 * stride], src[5 * stride]);
        t.u[3] = pkh(src[6 * stride], src[7 * stride]);
        *(f16x8*)(wlds + F * 8) = t.v;
    }

    // ---- per-wave x tiles: wave owns rows rb..rb+31 (two 16-row tiles).
    const int rb = blockIdx.x * 512 + w * 32;
    const float* xp0 = x + (size_t)(rb + n) * 32 + q * 8;
    const float* xp1 = xp0 + 16 * 32;
    const f32x4 xa0 = *(const f32x4*)xp0, xb0 = *(const f32x4*)(xp0 + 4);
    const f32x4 xa1 = *(const f32x4*)xp1, xb1 = *(const f32x4*)(xp1 + 4);
    union { f16x8 v; unsigned u[4]; } xf0, xf1;
    xf0.u[0] = pkh(xa0.x, xa0.y); xf0.u[1] = pkh(xa0.z, xa0.w);
    xf0.u[2] = pkh(xb0.x, xb0.y); xf0.u[3] = pkh(xb0.z, xb0.w);
    xf1.u[0] = pkh(xa1.x, xa1.y); xf1.u[1] = pkh(xa1.z, xa1.w);
    xf1.u[2] = pkh(xb1.x, xb1.y); xf1.u[3] = pkh(xb1.z, xb1.w);

    __syncthreads();

    const short* wl = wlds + (n * 8 + q * 128);   // + e*2048/iter; imms do the rest
    const float* b1a = b1 + 8 * q;
    const float* b2a = b2 + 8 * q;
    const float* w3a = W3 + 8 * q;
    const float* pba = probs + (size_t)(rb + n) * 8;
    float r0 = 0.f, r1 = 0.f;

    #pragma unroll 2
    for (int e = 0; e < 8; ++e) {
        const float pb0 = pba[e], pb1 = pba[e + 128];
        const short* we = wl + e * 2048;

        // Layer 1: 4 mt-tiles; w1f shared by both row-tiles. pack+relu into
        // K=32 B-fragments P[kb2] (element j <-> h = 32kb2 + 8q + j).
        union { f16x8 v; unsigned u[4]; } P0[2], P1[2];
        #pragma unroll
        for (int mt = 0; mt < 4; ++mt) {
            const f16x8 w1f = *(const f16x8*)(we + mt * 512);
            const f32x4 bf = *(const f32x4*)(b1a + e * 64 + 32 * (mt >> 1) + 4 * (mt & 1));
            const f32x4 c0 = MFMA32(w1f, xf0.v, bf);
            const f32x4 c1 = MFMA32(w1f, xf1.v, bf);
            P0[mt >> 1].u[(mt & 1) * 2 + 0] = relu2(pkh(c0.x, c0.y));
            P0[mt >> 1].u[(mt & 1) * 2 + 1] = relu2(pkh(c0.z, c0.w));
            P1[mt >> 1].u[(mt & 1) * 2 + 0] = relu2(pkh(c1.x, c1.y));
            P1[mt >> 1].u[(mt & 1) * 2 + 1] = relu2(pkh(c1.z, c1.w));
        }

        // Layer 2: 2 mt2 x 2 kb2; pack+relu into PC (element j <-> h2 = 8q+j).
        union { f16x8 v; unsigned u[4]; } PC0, PC1;
        #pragma unroll
        for (int mt2 = 0; mt2 < 2; ++mt2) {
            const f32x4 bf = *(const f32x4*)(b2a + e * 32 + 4 * mt2);
            f32x4 c0 = bf, c1 = bf;
            #pragma unroll
            for (int kb2 = 0; kb2 < 2; ++kb2) {
                const f16x8 w2f =
                    *(const f16x8*)(we + 16384 + mt2 * 512 + kb2 * 1024);
                c0 = MFMA32(w2f, P0[kb2].v, c0);
                c1 = MFMA32(w2f, P1[kb2].v, c1);
            }
            PC0.u[mt2 * 2 + 0] = relu2(pkh(c0.x, c0.y));
            PC0.u[mt2 * 2 + 1] = relu2(pkh(c0.z, c0.w));
            PC1.u[mt2 * 2 + 0] = relu2(pkh(c1.x, c1.y));
            PC1.u[mt2 * 2 + 1] = relu2(pkh(c1.z, c1.w));
        }

        // Layer 3: A = w3 replicated over rows -> D[m][n] = s[n] for all m.
        // b3 seeded into the C operand.
        const f32x4 w3lo = *(const f32x4*)(w3a + e * 32);
        const f32x4 w3hi = *(const f32x4*)(w3a + e * 32 + 4);
        union { f16x8 v; unsigned u[4]; } a3;
        a3.u[0] = pkh(w3lo.x, w3lo.y); a3.u[1] = pkh(w3lo.z, w3lo.w);
        a3.u[2] = pkh(w3hi.x, w3hi.y); a3.u[3] = pkh(w3hi.z, w3hi.w);
        const float bb = b3[e];   // wave-uniform -> scalar load
        const f32x4 cb = {bb, bb, bb, bb};
        const f32x4 s0 = MFMA32(a3.v, PC0.v, cb);
        const f32x4 s1 = MFMA32(a3.v, PC1.v, cb);

        r0 = fmaf(1.f / (1.f + __expf(-s0.x)), pb0, r0);
        r1 = fmaf(1.f / (1.f + __expf(-s1.x)), pb1, r1);
    }

    if (q == 0) {
        out[rb + n] = r0;
        out[rb + 16 + n] = r1;
    }
}

extern "C" void kernel_launch(void* const* d_in, const int* in_sizes, int n_in,
                              void* d_out, int out_size, void* d_ws, size_t ws_size,
                              hipStream_t stream) {
    const float* x     = (const float*)d_in[0];
    const float* probs = (const float*)d_in[1];
    const float* W1    = (const float*)d_in[2];
    const float* b1    = (const float*)d_in[3];
    const float* W2    = (const float*)d_in[4];
    const float* b2    = (const float*)d_in[5];
    const float* W3    = (const float*)d_in[6];
    const float* b3    = (const float*)d_in[7];

    const int nrows = in_sizes[0] / 32;          // 524288
    hipLaunchKernelGGL(moe_fused, dim3(nrows / 512), dim3(1024), 0, stream,
                       x, probs, W1, b1, W2, b2, W3, b3, (float*)d_out);
}

// Round 4
// 145.098 us; speedup vs baseline: 1.2218x; 1.0716x over previous
//
#include <hip/hip_runtime.h>

// EnhancedMoEModel: B=524288, D=32, H=64, H2=32, E=8, O=1. fp32 in/out.
// out[b] = sum_e sigmoid(relu(relu(x W1e + b1e) W2e + b2e) W3e + b3e) * probs[b,e]
//
// R13b: R13 with the LDS-copy tail fixed (was tid<224 = 3584 B, which
// missed b3 at image bytes [69120,69152) -> garbage bias, absmax 2.34).
// Tail is now 226 fragments (3616 B).
//
// R13 design: kill redundant per-block prologue + in-loop VMEM:
//  - build_image pre-kernel (1 block) decodes W1/W2 into MFMA fragment
//    layout ONCE into d_ws, plus bias f32x4 fragments, pre-packed f16 W3
//    fragments, and b3 (69152 B total). Main blocks copy it linearly.
//  - all per-expert constants read from LDS (broadcast, conflict-free).
//  - expert loop unroll 4.
//
// Fragment math (verified R8/R10 end-to-end, dtype-independent C/D layout):
// 16x16x32 MFMA with A[m=lane&15][k=8q+j], B[k=8q+j][n=lane&15],
// D[m=4q+r][n]: per-lane reg r. Hidden-unit column permutation
// hmap(mt,n)=32(mt>>1)+8(n>>2)+4(mt&1)+(n&3) makes layer-N output registers
// exactly the next layer's B-fragment.
//
// LDS/ws image layout (byte offsets):
//   [0,      65536): weight frags, 16B each, F = addr/16:
//       w1: F = e*256 + 64*mt + 16*q + n
//       w2: F = 2048 + e*256 + 128*kb2 + 64*mt2 + 16*q + n
//   [65536, 67584): b1 frags  f32x4, idx = e*16 + mt*4 + q
//                   = b1[e][32(mt>>1)+4(mt&1)+8q ..+3]
//   [67584, 68608): b2 frags  f32x4, idx = e*8 + mt2*4 + q
//                   = b2[e][4*mt2+8q ..+3]
//   [68608, 69120): a3 frags  f16x8, idx = e*4 + q = pkh(W3[e][8q..8q+7])
//   [69120, 69152): b3[0..7] f32

typedef __attribute__((ext_vector_type(8))) _Float16 f16x8;
typedef __attribute__((ext_vector_type(2))) __fp16 h16x2;
typedef __attribute__((ext_vector_type(4))) float f32x4;

__device__ __forceinline__ unsigned pkh(float lo, float hi) {
    union { h16x2 v; unsigned u; } t;
    t.v = __builtin_amdgcn_cvt_pkrtz(lo, hi);
    return t.u;
}

// packed relu on 2 x f16 (relu-after-pack == relu-before-pack for RTZ)
__device__ __forceinline__ unsigned relu2(unsigned a) {
    unsigned r;
    asm("v_pk_max_f16 %0, %1, 0" : "=v"(r) : "v"(a));
    return r;
}

#define MFMA32(a, b, c) __builtin_amdgcn_mfma_f32_16x16x32_f16((a), (b), (c), 0, 0, 0)

__global__ __launch_bounds__(1024)
void build_image(const float* __restrict__ W1, const float* __restrict__ b1,
                 const float* __restrict__ W2, const float* __restrict__ b2,
                 const float* __restrict__ W3, const float* __restrict__ b3,
                 char* __restrict__ ws) {
    const int tid = threadIdx.x;
    // weight fragments: 4096, 4 per thread (decode identical to R12b)
    #pragma unroll
    for (int k = 0; k < 4; ++k) {
        const int F = tid + k * 1024;
        const int e = (F >> 8) & 7, s = F & 255;
        const int qq = (s >> 4) & 3, nn = s & 15;
        const float* src;
        int stride;
        if (F < 2048) {          // W1[e][d=8qq+j][hmap(mt,nn)], j strides d
            const int mt = s >> 6;
            const int h = 32 * (mt >> 1) + 8 * (nn >> 2) + 4 * (mt & 1) + (nn & 3);
            src = W1 + (e * 32 + 8 * qq) * 64 + h;
            stride = 64;
        } else {                 // W2[e][h=32kb2+8qq+j][h2map(mt2,nn)], j strides h
            const int kb2 = (s >> 7) & 1, mt2 = (s >> 6) & 1;
            const int h2 = 8 * (nn >> 2) + 4 * mt2 + (nn & 3);
            src = W2 + (e * 64 + 32 * kb2 + 8 * qq) * 32 + h2;
            stride = 32;
        }
        union { f16x8 v; unsigned u[4]; } t;
        t.u[0] = pkh(src[0 * stride], src[1 * stride]);
        t.u[1] = pkh(src[2 * stride], src[3 * stride]);
        t.u[2] = pkh(src[4 * stride], src[5 * stride]);
        t.u[3] = pkh(src[6 * stride], src[7 * stride]);
        *(f16x8*)(ws + F * 16) = t.v;
    }
    if (tid < 128) {                       // b1 frags
        const int e = tid >> 4, mt = (tid >> 2) & 3, q = tid & 3;
        *(f32x4*)(ws + 65536 + tid * 16) =
            *(const f32x4*)(b1 + e * 64 + 32 * (mt >> 1) + 4 * (mt & 1) + 8 * q);
    } else if (tid < 192) {                // b2 frags
        const int i = tid - 128, e = i >> 3, mt2 = (i >> 2) & 1, q = i & 3;
        *(f32x4*)(ws + 67584 + i * 16) =
            *(const f32x4*)(b2 + e * 32 + 4 * mt2 + 8 * q);
    } else if (tid < 224) {                // a3 frags (pre-packed f16)
        const int i = tid - 192, e = i >> 2, q = i & 3;
        const f32x4 lo = *(const f32x4*)(W3 + e * 32 + 8 * q);
        const f32x4 hi = *(const f32x4*)(W3 + e * 32 + 8 * q + 4);
        union { f16x8 v; unsigned u[4]; } a;
        a.u[0] = pkh(lo.x, lo.y); a.u[1] = pkh(lo.z, lo.w);
        a.u[2] = pkh(hi.x, hi.y); a.u[3] = pkh(hi.z, hi.w);
        *(f16x8*)(ws + 68608 + i * 16) = a.v;
    } else if (tid < 232) {                // b3
        const int i = tid - 224;
        *(float*)(ws + 69120 + i * 4) = b3[i];
    }
}

__global__ __launch_bounds__(1024, 8)
void moe_fused(const float* __restrict__ x, const float* __restrict__ probs,
               const char* __restrict__ img, float* __restrict__ out) {
    __shared__ __attribute__((aligned(16))) char ldsraw[69632];
    const int tid = threadIdx.x;
    const int w = tid >> 6, lane = tid & 63, n = lane & 15, q = lane >> 4;

    // ---- prologue: linear coalesced copy of the prebuilt image.
    #pragma unroll
    for (int k = 0; k < 4; ++k) {
        const int off = tid * 16 + k * 16384;
        *(f32x4*)(ldsraw + off) = *(const f32x4*)(img + off);
    }
    if (tid < 226) {                        // tail 3616 B incl. b3
        const int off = 65536 + tid * 16;
        *(f32x4*)(ldsraw + off) = *(const f32x4*)(img + off);
    }

    // ---- per-wave x tiles: wave owns rows rb..rb+31 (two 16-row tiles).
    const int rb = blockIdx.x * 512 + w * 32;
    const float* xp0 = x + (size_t)(rb + n) * 32 + q * 8;
    const float* xp1 = xp0 + 16 * 32;
    const f32x4 xa0 = *(const f32x4*)xp0, xb0 = *(const f32x4*)(xp0 + 4);
    const f32x4 xa1 = *(const f32x4*)xp1, xb1 = *(const f32x4*)(xp1 + 4);
    union { f16x8 v; unsigned u[4]; } xf0, xf1;
    xf0.u[0] = pkh(xa0.x, xa0.y); xf0.u[1] = pkh(xa0.z, xa0.w);
    xf0.u[2] = pkh(xb0.x, xb0.y); xf0.u[3] = pkh(xb0.z, xb0.w);
    xf1.u[0] = pkh(xa1.x, xa1.y); xf1.u[1] = pkh(xa1.z, xa1.w);
    xf1.u[2] = pkh(xb1.x, xb1.y); xf1.u[3] = pkh(xb1.z, xb1.w);

    __syncthreads();

    const short* wl = (const short*)ldsraw + (n * 8 + q * 128);
    const char* bb1 = ldsraw + 65536 + q * 16;   // + e*256 + mt*64
    const char* bb2 = ldsraw + 67584 + q * 16;   // + e*128 + mt2*64
    const char* ba3 = ldsraw + 68608 + q * 16;   // + e*64
    const float* pba = probs + (size_t)(rb + n) * 8;
    float r0 = 0.f, r1 = 0.f;

    #pragma unroll 4
    for (int e = 0; e < 8; ++e) {
        const float pb0 = pba[e], pb1 = pba[e + 128];
        const short* we = wl + e * 2048;

        // Layer 1: 4 mt-tiles; w1f shared by both row-tiles. pack+relu into
        // K=32 B-fragments P[kb2] (element j <-> h = 32kb2 + 8q + j).
        union { f16x8 v; unsigned u[4]; } P0[2], P1[2];
        #pragma unroll
        for (int mt = 0; mt < 4; ++mt) {
            const f16x8 w1f = *(const f16x8*)(we + mt * 512);
            const f32x4 bf = *(const f32x4*)(bb1 + e * 256 + mt * 64);
            const f32x4 c0 = MFMA32(w1f, xf0.v, bf);
            const f32x4 c1 = MFMA32(w1f, xf1.v, bf);
            P0[mt >> 1].u[(mt & 1) * 2 + 0] = relu2(pkh(c0.x, c0.y));
            P0[mt >> 1].u[(mt & 1) * 2 + 1] = relu2(pkh(c0.z, c0.w));
            P1[mt >> 1].u[(mt & 1) * 2 + 0] = relu2(pkh(c1.x, c1.y));
            P1[mt >> 1].u[(mt & 1) * 2 + 1] = relu2(pkh(c1.z, c1.w));
        }

        // Layer 2: 2 mt2 x 2 kb2; pack+relu into PC (element j <-> h2 = 8q+j).
        union { f16x8 v; unsigned u[4]; } PC0, PC1;
        #pragma unroll
        for (int mt2 = 0; mt2 < 2; ++mt2) {
            const f32x4 bf = *(const f32x4*)(bb2 + e * 128 + mt2 * 64);
            f32x4 c0 = bf, c1 = bf;
            #pragma unroll
            for (int kb2 = 0; kb2 < 2; ++kb2) {
                const f16x8 w2f =
                    *(const f16x8*)(we + 16384 + mt2 * 512 + kb2 * 1024);
                c0 = MFMA32(w2f, P0[kb2].v, c0);
                c1 = MFMA32(w2f, P1[kb2].v, c1);
            }
            PC0.u[mt2 * 2 + 0] = relu2(pkh(c0.x, c0.y));
            PC0.u[mt2 * 2 + 1] = relu2(pkh(c0.z, c0.w));
            PC1.u[mt2 * 2 + 0] = relu2(pkh(c1.x, c1.y));
            PC1.u[mt2 * 2 + 1] = relu2(pkh(c1.z, c1.w));
        }

        // Layer 3: A = pre-packed w3 frag; b3 seeded into C operand.
        const f16x8 a3v = *(const f16x8*)(ba3 + e * 64);
        const float bb = *(const float*)(ldsraw + 69120 + e * 4);  // uniform
        const f32x4 cb = {bb, bb, bb, bb};
        const f32x4 s0 = MFMA32(a3v, PC0.v, cb);
        const f32x4 s1 = MFMA32(a3v, PC1.v, cb);

        r0 = fmaf(1.f / (1.f + __expf(-s0.x)), pb0, r0);
        r1 = fmaf(1.f / (1.f + __expf(-s1.x)), pb1, r1);
    }

    if (q == 0) {
        out[rb + n] = r0;
        out[rb + 16 + n] = r1;
    }
}

extern "C" void kernel_launch(void* const* d_in, const int* in_sizes, int n_in,
                              void* d_out, int out_size, void* d_ws, size_t ws_size,
                              hipStream_t stream) {
    const float* x     = (const float*)d_in[0];
    const float* probs = (const float*)d_in[1];
    const float* W1    = (const float*)d_in[2];
    const float* b1    = (const float*)d_in[3];
    const float* W2    = (const float*)d_in[4];
    const float* b2    = (const float*)d_in[5];
    const float* W3    = (const float*)d_in[6];
    const float* b3    = (const float*)d_in[7];

    hipLaunchKernelGGL(build_image, dim3(1), dim3(1024), 0, stream,
                       W1, b1, W2, b2, W3, b3, (char*)d_ws);
    const int nrows = in_sizes[0] / 32;          // 524288
    hipLaunchKernelGGL(moe_fused, dim3(nrows / 512), dim3(1024), 0, stream,
                       x, probs, (const char*)d_ws, (float*)d_out);
}